// Round 9
// baseline (36.949 us; speedup 1.0000x reference)
//
#include <hip/hip_runtime.h>

typedef __attribute__((ext_vector_type(8))) short bf16x8;
typedef __attribute__((ext_vector_type(4))) float f32x4;

#define EPS 1e-5f
#define K2L 2.8853900817779268f   // 2*log2(e): folds exp(2y) -> exp2(y*K2L)

// ws layout: frag blocks (182 x 1KB bf16) then fp32 ST region
#define N_FRAG_BLOCKS 182
#define WSB_LEAF 0      // 64 blocks: leaf l
#define WSB_MID  64     // 80 blocks: m*10 + tt*5 + s
#define WSB_ROOT 144    // 36 blocks: tt*9 + s
#define WSB_HEAD 180    // 2 blocks: s
#define ST_SL 0
#define ST_TL 1024
#define ST_SM 2048
#define ST_TM 2304
#define ST_SR 2560
#define ST_TR 2624
#define WS_ST_BYTE_OFF (N_FRAG_BLOCKS * 1024)

__device__ __forceinline__ unsigned short f2bf(float f) {  // RNE float->bf16
    unsigned u = __float_as_uint(f);
    unsigned r = u + 0x7fffu + ((u >> 16) & 1u);
    return (unsigned short)(r >> 16);
}

// HW packed f32x2 -> bf16x2 (RNE), 1 instruction
__device__ __forceinline__ unsigned cvt_pk(float a, float b) {
    unsigned r;
    asm("v_cvt_pk_bf16_f32 %0, %1, %2" : "=v"(r) : "v"(a), "v"(b));
    return r;
}

__device__ __forceinline__ bf16x8 pack8(float4 a, float4 b) {
    union { unsigned u[4]; bf16x8 v; } r;
    r.u[0] = cvt_pk(a.x, a.y); r.u[1] = cvt_pk(a.z, a.w);
    r.u[2] = cvt_pk(b.x, b.y); r.u[3] = cvt_pk(b.z, b.w);
    return r.v;
}

// BN+tanh with pre-folded scale: arg = acc*S' + T' (S',T' carry 2*log2e)
__device__ __forceinline__ float bn_act(float acc, float Sp, float Tp) {
    float e = exp2f(fmaf(acc, Sp, Tp));
    float r = __builtin_amdgcn_rcpf(e + 1.0f);
    return fmaf(-2.0f, r, 1.0f);
}

// ---------------- prep: fragment-ordered bf16 weights + folded BN ----------
__global__ void ontology_prep(
    const float* __restrict__ Wl, const float* __restrict__ Wm,
    const float* __restrict__ Wr, const float* __restrict__ Wh,
    const float* __restrict__ bl, const float* __restrict__ gl,
    const float* __restrict__ betal, const float* __restrict__ ml,
    const float* __restrict__ vl,
    const float* __restrict__ bm, const float* __restrict__ gm,
    const float* __restrict__ betam, const float* __restrict__ mm,
    const float* __restrict__ vm,
    const float* __restrict__ br, const float* __restrict__ gr,
    const float* __restrict__ betar, const float* __restrict__ mr,
    const float* __restrict__ vr,
    unsigned short* __restrict__ wsFrag, float* __restrict__ wsST)
{
    const int b = blockIdx.x;
    const int t = threadIdx.x;
    if (b < N_FRAG_BLOCKS) {
        // A'-frag (transposed weights): lane t holds A'[row=t&15][k=(t>>4)*8+i]
        const int row = t & 15, g = t >> 4;
        unsigned short vals[8];
        #pragma unroll
        for (int i = 0; i < 8; ++i) {
            const int k = g * 8 + i;
            float v = 0.f;
            if (b < 64) {                       // leaf l: pair-packed K
                const int l = b;
                if ((l & 1) == 0) { if (k < 16)  v = Wl[l * 256 + k * 16 + row]; }
                else              { if (k >= 16) v = Wl[l * 256 + (k - 16) * 16 + row]; }
            } else if (b < 144) {               // mid: m*10 + tt*5 + s
                const int idx = b - 64, m = idx / 10, rem = idx % 10;
                const int tt = rem / 5, s = rem % 5;
                const int krow = s * 32 + k;
                if (krow < 144) v = Wm[m * 4608 + krow * 32 + tt * 16 + row];
            } else if (b < 180) {               // root: tt*9 + s
                const int idx = b - 144, tt = idx / 9, s = idx % 9;
                if (s == 0) { if (k < 16) v = Wr[k * 64 + tt * 16 + row]; }
                else { const int krow = 16 + (s - 1) * 32 + k;
                       v = Wr[krow * 64 + tt * 16 + row]; }
            } else {                            // head
                const int s = b - 180, krow = s * 32 + k;
                if (row < 10) v = Wh[krow * 10 + row];
            }
            vals[i] = f2bf(v);
        }
        #pragma unroll
        for (int i = 0; i < 8; ++i) wsFrag[b * 512 + t * 8 + i] = vals[i];
    } else if (b == N_FRAG_BLOCKS) {            // leaf ST (1024), folded by K2L
        for (int i = 0; i < 16; ++i) {
            const int id = t + 64 * i;
            const float S = gl[id] * rsqrtf(vl[id] + EPS);
            wsST[ST_SL + id] = S * K2L;
            wsST[ST_TL + id] = ((bl[id] - ml[id]) * S + betal[id]) * K2L;
        }
    } else if (b == N_FRAG_BLOCKS + 1) {        // mid ST (256)
        for (int i = 0; i < 4; ++i) {
            const int id = t + 64 * i;
            const float S = gm[id] * rsqrtf(vm[id] + EPS);
            wsST[ST_SM + id] = S * K2L;
            wsST[ST_TM + id] = ((bm[id] - mm[id]) * S + betam[id]) * K2L;
        }
    } else {                                     // root ST (64)
        const int id = t;
        const float S = gr[id] * rsqrtf(vr[id] + EPS);
        wsST[ST_SR + id] = S * K2L;
        wsST[ST_TR + id] = ((br[id] - mr[id]) * S + betar[id]) * K2L;
    }
}

// ---------------- main fused MFMA kernel: independent waves ----------------
// Block = 256 thr = 4 waves = one 16-sample tile. Wave w self-contained for
// mids {w, w+4}; iter-1 x loads issued mid-iter-0 (single HBM stall/wave).
// Cross-wave root K-sum via f32 LDS slab, 2 rounds. 4 barriers total.
__global__ __launch_bounds__(256, 4) void ontology_mfma(
    const float* __restrict__ x,
    const unsigned short* __restrict__ wsFrag,
    const float* __restrict__ wsST,
    const float* __restrict__ bh,
    float* __restrict__ out)
{
    __shared__ __align__(16) unsigned short mid_in[4][16][168]; // 21.0 KB
    __shared__ __align__(16) unsigned short hm[4][16][40];      //  2.5 KB
    __shared__ __align__(16) float slab[4][16][34];             //  8.5 KB
    unsigned short (*hr)[72] = (unsigned short (*)[72])&mid_in[0][0][0]; // alias (dead)

    const int tid  = threadIdx.x;
    const int w    = tid >> 6;
    const int lane = tid & 63;
    const int c    = lane & 15;       // sample within tile
    const int g    = lane >> 4;       // k/feat group
    const int rowbase = blockIdx.x * 16;
    const float* xrow = x + (size_t)(rowbase + c) * 1168;

    const float* Sl = wsST + ST_SL; const float* Tl = wsST + ST_TL;
    const float* Sm = wsST + ST_SM; const float* Tm = wsST + ST_TM;
    const float* Sr = wsST + ST_SR; const float* Tr = wsST + ST_TR;

    const int M0 = w, M1 = w + 4;

    // ---- iter0 x loads (9 float4) + root-x (wave 3) ----
    float4 xmA = *(const float4*)(xrow + 1024 + M0 * 16 + 4 * g);
    float4 xpA[4][2];
    #pragma unroll
    for (int p = 0; p < 4; ++p) {
        const float* a = xrow + (M0 * 4 + p) * 32 + g * 8;
        xpA[p][0] = *(const float4*)a;
        xpA[p][1] = *(const float4*)(a + 4);
    }
    float4 xrA, xrB;
    if (w == 3) {
        const float* rp = xrow + 1152 + (g & 1) * 8;
        xrA = *(const float4*)rp;
        xrB = *(const float4*)(rp + 4);
    }

    // zero own K-pad cols 144..159 (read by mid s=4)
    { uint2 z; z.x = 0u; z.y = 0u; *(uint2*)&mid_in[w][c][144 + 4 * g] = z; }

    f32x4 accR[4];
    #pragma unroll
    for (int t = 0; t < 4; ++t) { f32x4 z0 = {0.f,0.f,0.f,0.f}; accR[t] = z0; }

    // ---- iter0: pack B-frags (xpA dies here) ----
    bf16x8 bfA[4];
    #pragma unroll
    for (int p = 0; p < 4; ++p) bfA[p] = pack8(xpA[p][0], xpA[p][1]);
    { uint2 pm; pm.x = cvt_pk(xmA.x, xmA.y); pm.y = cvt_pk(xmA.z, xmA.w);
      *(uint2*)&mid_in[w][c][4 * g] = pm; }

    // ---- issue iter1 x loads NOW (hidden under iter0 compute) ----
    float4 xmB = *(const float4*)(xrow + 1024 + M1 * 16 + 4 * g);
    float4 xpB[4][2];
    #pragma unroll
    for (int p = 0; p < 4; ++p) {
        const float* a = xrow + (M1 * 4 + p) * 32 + g * 8;
        xpB[p][0] = *(const float4*)a;
        xpB[p][1] = *(const float4*)(a + 4);
    }

    // ================= iter 0: leaves + mid + root partial =================
    #pragma unroll
    for (int p = 0; p < 4; ++p) {
        #pragma unroll
        for (int e = 0; e < 2; ++e) {
            const int l = 2 * p + e, leaf = M0 * 8 + l;
            bf16x8 afrag = *(const bf16x8*)(wsFrag + (WSB_LEAF + leaf) * 512 + lane * 8);
            f32x4 zz = {0.f,0.f,0.f,0.f};
            f32x4 acc = __builtin_amdgcn_mfma_f32_16x16x32_bf16(afrag, bfA[p], zz, 0, 0, 0);
            const int po = leaf * 16 + 4 * g;
            float4 S = *(const float4*)(Sl + po);
            float4 T = *(const float4*)(Tl + po);
            uint2 pk;
            pk.x = cvt_pk(bn_act(acc[0], S.x, T.x), bn_act(acc[1], S.y, T.y));
            pk.y = cvt_pk(bn_act(acc[2], S.z, T.z), bn_act(acc[3], S.w, T.w));
            *(uint2*)&mid_in[w][c][16 + l * 16 + 4 * g] = pk;
        }
    }
    #pragma unroll
    for (int tt = 0; tt < 2; ++tt) {
        f32x4 acc = {0.f,0.f,0.f,0.f};
        const unsigned short* fb = wsFrag + (WSB_MID + M0 * 10 + tt * 5) * 512 + lane * 8;
        #pragma unroll
        for (int s = 0; s < 5; ++s) {
            bf16x8 bfrag = *(const bf16x8*)&mid_in[w][c][s * 32 + g * 8];
            bf16x8 a0 = *(const bf16x8*)(fb + s * 512);
            acc = __builtin_amdgcn_mfma_f32_16x16x32_bf16(a0, bfrag, acc, 0, 0, 0);
        }
        const int po = M0 * 32 + tt * 16 + 4 * g;
        float4 S = *(const float4*)(Sm + po);
        float4 T = *(const float4*)(Tm + po);
        uint2 pk;
        pk.x = cvt_pk(bn_act(acc[0], S.x, T.x), bn_act(acc[1], S.y, T.y));
        pk.y = cvt_pk(bn_act(acc[2], S.z, T.z), bn_act(acc[3], S.w, T.w));
        *(uint2*)&hm[w][c][tt * 16 + 4 * g] = pk;
    }
    {
        bf16x8 bfrag = *(const bf16x8*)&hm[w][c][g * 8];
        #pragma unroll
        for (int t = 0; t < 4; ++t) {
            bf16x8 a = *(const bf16x8*)(wsFrag + (WSB_ROOT + t * 9 + M0 + 1) * 512 + lane * 8);
            accR[t] = __builtin_amdgcn_mfma_f32_16x16x32_bf16(a, bfrag, accR[t], 0, 0, 0);
        }
    }

    // ================= iter 1 =================
    bf16x8 bfB[4];
    #pragma unroll
    for (int p = 0; p < 4; ++p) bfB[p] = pack8(xpB[p][0], xpB[p][1]);
    { uint2 pm; pm.x = cvt_pk(xmB.x, xmB.y); pm.y = cvt_pk(xmB.z, xmB.w);
      *(uint2*)&mid_in[w][c][4 * g] = pm; }
    #pragma unroll
    for (int p = 0; p < 4; ++p) {
        #pragma unroll
        for (int e = 0; e < 2; ++e) {
            const int l = 2 * p + e, leaf = M1 * 8 + l;
            bf16x8 afrag = *(const bf16x8*)(wsFrag + (WSB_LEAF + leaf) * 512 + lane * 8);
            f32x4 zz = {0.f,0.f,0.f,0.f};
            f32x4 acc = __builtin_amdgcn_mfma_f32_16x16x32_bf16(afrag, bfB[p], zz, 0, 0, 0);
            const int po = leaf * 16 + 4 * g;
            float4 S = *(const float4*)(Sl + po);
            float4 T = *(const float4*)(Tl + po);
            uint2 pk;
            pk.x = cvt_pk(bn_act(acc[0], S.x, T.x), bn_act(acc[1], S.y, T.y));
            pk.y = cvt_pk(bn_act(acc[2], S.z, T.z), bn_act(acc[3], S.w, T.w));
            *(uint2*)&mid_in[w][c][16 + l * 16 + 4 * g] = pk;
        }
    }
    #pragma unroll
    for (int tt = 0; tt < 2; ++tt) {
        f32x4 acc = {0.f,0.f,0.f,0.f};
        const unsigned short* fb = wsFrag + (WSB_MID + M1 * 10 + tt * 5) * 512 + lane * 8;
        #pragma unroll
        for (int s = 0; s < 5; ++s) {
            bf16x8 bfrag = *(const bf16x8*)&mid_in[w][c][s * 32 + g * 8];
            bf16x8 a0 = *(const bf16x8*)(fb + s * 512);
            acc = __builtin_amdgcn_mfma_f32_16x16x32_bf16(a0, bfrag, acc, 0, 0, 0);
        }
        const int po = M1 * 32 + tt * 16 + 4 * g;
        float4 S = *(const float4*)(Sm + po);
        float4 T = *(const float4*)(Tm + po);
        uint2 pk;
        pk.x = cvt_pk(bn_act(acc[0], S.x, T.x), bn_act(acc[1], S.y, T.y));
        pk.y = cvt_pk(bn_act(acc[2], S.z, T.z), bn_act(acc[3], S.w, T.w));
        *(uint2*)&hm[w][c][tt * 16 + 4 * g] = pk;
    }
    {
        bf16x8 bfrag = *(const bf16x8*)&hm[w][c][g * 8];
        #pragma unroll
        for (int t = 0; t < 4; ++t) {
            bf16x8 a = *(const bf16x8*)(wsFrag + (WSB_ROOT + t * 9 + M1 + 1) * 512 + lane * 8);
            accR[t] = __builtin_amdgcn_mfma_f32_16x16x32_bf16(a, bfrag, accR[t], 0, 0, 0);
        }
    }

    // root K-step s=0 (wave 3; x cols 1152..; A' rows k>=16 are 0)
    if (w == 3) {
        bf16x8 bfrag = pack8(xrA, xrB);
        #pragma unroll
        for (int t = 0; t < 4; ++t) {
            bf16x8 a = *(const bf16x8*)(wsFrag + (WSB_ROOT + t * 9) * 512 + lane * 8);
            accR[t] = __builtin_amdgcn_mfma_f32_16x16x32_bf16(a, bfrag, accR[t], 0, 0, 0);
        }
    }

    // ---- cross-wave root combine, round A (col-tiles 0,1) ------------------
    #pragma unroll
    for (int t = 0; t < 2; ++t) {
        float2 lo; lo.x = accR[t][0]; lo.y = accR[t][1];
        float2 hi; hi.x = accR[t][2]; hi.y = accR[t][3];
        *(float2*)&slab[w][c][t * 16 + 4 * g]     = lo;
        *(float2*)&slab[w][c][t * 16 + 4 * g + 2] = hi;
    }
    asm volatile("s_waitcnt lgkmcnt(0)" ::: "memory");
    __builtin_amdgcn_s_barrier();
    if (w < 2) {
        float4 sum = {0.f,0.f,0.f,0.f};
        #pragma unroll
        for (int v = 0; v < 4; ++v) {
            float2 lo = *(const float2*)&slab[v][c][w * 16 + 4 * g];
            float2 hi = *(const float2*)&slab[v][c][w * 16 + 4 * g + 2];
            sum.x += lo.x; sum.y += lo.y; sum.z += hi.x; sum.w += hi.y;
        }
        const int po = w * 16 + 4 * g;
        float4 S = *(const float4*)(Sr + po);
        float4 T = *(const float4*)(Tr + po);
        uint2 pk;
        pk.x = cvt_pk(bn_act(sum.x, S.x, T.x), bn_act(sum.y, S.y, T.y));
        pk.y = cvt_pk(bn_act(sum.z, S.z, T.z), bn_act(sum.w, S.w, T.w));
        *(uint2*)&hr[c][po] = pk;   // hr aliases mid_in (dead after loop)
    }
    asm volatile("s_waitcnt lgkmcnt(0)" ::: "memory");
    __builtin_amdgcn_s_barrier();

    // ---- round B (col-tiles 2,3 at slab positions 0,1) ---------------------
    #pragma unroll
    for (int t = 2; t < 4; ++t) {
        float2 lo; lo.x = accR[t][0]; lo.y = accR[t][1];
        float2 hi; hi.x = accR[t][2]; hi.y = accR[t][3];
        *(float2*)&slab[w][c][(t - 2) * 16 + 4 * g]     = lo;
        *(float2*)&slab[w][c][(t - 2) * 16 + 4 * g + 2] = hi;
    }
    asm volatile("s_waitcnt lgkmcnt(0)" ::: "memory");
    __builtin_amdgcn_s_barrier();
    if (w >= 2) {
        float4 sum = {0.f,0.f,0.f,0.f};
        #pragma unroll
        for (int v = 0; v < 4; ++v) {
            float2 lo = *(const float2*)&slab[v][c][(w - 2) * 16 + 4 * g];
            float2 hi = *(const float2*)&slab[v][c][(w - 2) * 16 + 4 * g + 2];
            sum.x += lo.x; sum.y += lo.y; sum.z += hi.x; sum.w += hi.y;
        }
        const int po = w * 16 + 4 * g;
        float4 S = *(const float4*)(Sr + po);
        float4 T = *(const float4*)(Tr + po);
        uint2 pk;
        pk.x = cvt_pk(bn_act(sum.x, S.x, T.x), bn_act(sum.y, S.y, T.y));
        pk.y = cvt_pk(bn_act(sum.z, S.z, T.z), bn_act(sum.w, S.w, T.w));
        *(uint2*)&hr[c][po] = pk;
    }
    asm volatile("s_waitcnt lgkmcnt(0)" ::: "memory");
    __builtin_amdgcn_s_barrier();

    // ---- head (wave 0): tasks in rows, samples in cols ---------------------
    if (w == 0) {
        f32x4 acc = {0.f,0.f,0.f,0.f};
        #pragma unroll
        for (int s = 0; s < 2; ++s) {
            bf16x8 bfrag = *(const bf16x8*)&hr[c][s * 32 + g * 8];
            bf16x8 a0 = *(const bf16x8*)(wsFrag + (WSB_HEAD + s) * 512 + lane * 8);
            acc = __builtin_amdgcn_mfma_f32_16x16x32_bf16(a0, bfrag, acc, 0, 0, 0);
        }
        float* op = out + (size_t)(rowbase + c) * 10 + 4 * g;
        if (g < 2) {
            float2 o1 = {acc[0] + bh[4 * g],     acc[1] + bh[4 * g + 1]};
            float2 o2 = {acc[2] + bh[4 * g + 2], acc[3] + bh[4 * g + 3]};
            *(float2*)op = o1;
            *(float2*)(op + 2) = o2;
        } else if (g == 2) {
            float2 o1 = {acc[0] + bh[8], acc[1] + bh[9]};
            *(float2*)op = o1;
        }
    }
}

extern "C" void kernel_launch(void* const* d_in, const int* in_sizes, int n_in,
                              void* d_out, int out_size, void* d_ws, size_t ws_size,
                              hipStream_t stream) {
    const float* x     = (const float*)d_in[0];
    const float* Wl    = (const float*)d_in[1];
    const float* bl    = (const float*)d_in[2];
    const float* gl    = (const float*)d_in[3];
    const float* betal = (const float*)d_in[4];
    const float* ml    = (const float*)d_in[5];
    const float* vl    = (const float*)d_in[6];
    const float* Wm    = (const float*)d_in[7];
    const float* bm    = (const float*)d_in[8];
    const float* gm    = (const float*)d_in[9];
    const float* betam = (const float*)d_in[10];
    const float* mm    = (const float*)d_in[11];
    const float* vm    = (const float*)d_in[12];
    const float* Wr    = (const float*)d_in[13];
    const float* br    = (const float*)d_in[14];
    const float* gr    = (const float*)d_in[15];
    const float* betar = (const float*)d_in[16];
    const float* mr    = (const float*)d_in[17];
    const float* vr    = (const float*)d_in[18];
    const float* Wh    = (const float*)d_in[19];
    const float* bh    = (const float*)d_in[20];
    float* out = (float*)d_out;

    unsigned short* wsFrag = (unsigned short*)d_ws;
    float* wsST = (float*)((char*)d_ws + WS_ST_BYTE_OFF);

    ontology_prep<<<N_FRAG_BLOCKS + 3, 64, 0, stream>>>(
        Wl, Wm, Wr, Wh, bl, gl, betal, ml, vl, bm, gm, betam, mm, vm,
        br, gr, betar, mr, vr, wsFrag, wsST);

    const int n = in_sizes[0] / 1168;   // 16384
    ontology_mfma<<<n / 16, 256, 0, stream>>>(x, wsFrag, wsST, bh, out);
}

// Round 10
// 31.932 us; speedup vs baseline: 1.1571x; 1.1571x over previous
//
#include <hip/hip_runtime.h>

typedef __attribute__((ext_vector_type(8))) short bf16x8;
typedef __attribute__((ext_vector_type(4))) float f32x4;

#define EPS 1e-5f
#define K2L 2.8853900817779268f   // 2*log2(e): folds exp(2y) -> exp2(y*K2L)

// ws layout: frag blocks (182 x 1KB bf16) then fp32 ST region
#define N_FRAG_BLOCKS 182
#define WSB_LEAF 0      // 64 blocks: leaf l
#define WSB_MID  64     // 80 blocks: m*10 + tt*5 + s
#define WSB_ROOT 144    // 36 blocks: tt*9 + s
#define WSB_HEAD 180    // 2 blocks: s
#define ST_SL 0
#define ST_TL 1024
#define ST_SM 2048
#define ST_TM 2304
#define ST_SR 2560
#define ST_TR 2624
#define WS_ST_BYTE_OFF (N_FRAG_BLOCKS * 1024)

__device__ __forceinline__ unsigned short f2bf(float f) {  // RNE float->bf16
    unsigned u = __float_as_uint(f);
    unsigned r = u + 0x7fffu + ((u >> 16) & 1u);
    return (unsigned short)(r >> 16);
}

__device__ __forceinline__ unsigned pack2bf(float a, float b) {
    return (unsigned)f2bf(a) | ((unsigned)f2bf(b) << 16);
}

__device__ __forceinline__ bf16x8 pack8(float4 a, float4 b) {
    union { unsigned u[4]; bf16x8 v; } r;
    r.u[0] = pack2bf(a.x, a.y); r.u[1] = pack2bf(a.z, a.w);
    r.u[2] = pack2bf(b.x, b.y); r.u[3] = pack2bf(b.z, b.w);
    return r.v;
}

// BN+tanh with pre-folded scale: arg = acc*S' + T' (S',T' carry 2*log2e)
__device__ __forceinline__ float bn_act(float acc, float Sp, float Tp) {
    float e = exp2f(fmaf(acc, Sp, Tp));
    float r = __builtin_amdgcn_rcpf(e + 1.0f);
    return fmaf(-2.0f, r, 1.0f);
}

// ---------------- prep: fragment-ordered bf16 weights + folded BN ----------
__global__ void ontology_prep(
    const float* __restrict__ Wl, const float* __restrict__ Wm,
    const float* __restrict__ Wr, const float* __restrict__ Wh,
    const float* __restrict__ bl, const float* __restrict__ gl,
    const float* __restrict__ betal, const float* __restrict__ ml,
    const float* __restrict__ vl,
    const float* __restrict__ bm, const float* __restrict__ gm,
    const float* __restrict__ betam, const float* __restrict__ mm,
    const float* __restrict__ vm,
    const float* __restrict__ br, const float* __restrict__ gr,
    const float* __restrict__ betar, const float* __restrict__ mr,
    const float* __restrict__ vr,
    unsigned short* __restrict__ wsFrag, float* __restrict__ wsST)
{
    const int b = blockIdx.x;
    const int t = threadIdx.x;
    if (b < N_FRAG_BLOCKS) {
        // A'-frag (transposed weights): lane t holds A'[row=t&15][k=(t>>4)*8+i]
        const int row = t & 15, g = t >> 4;
        unsigned short vals[8];
        #pragma unroll
        for (int i = 0; i < 8; ++i) {
            const int k = g * 8 + i;
            float v = 0.f;
            if (b < 64) {                       // leaf l: pair-packed K
                const int l = b;
                if ((l & 1) == 0) { if (k < 16)  v = Wl[l * 256 + k * 16 + row]; }
                else              { if (k >= 16) v = Wl[l * 256 + (k - 16) * 16 + row]; }
            } else if (b < 144) {               // mid: m*10 + tt*5 + s
                const int idx = b - 64, m = idx / 10, rem = idx % 10;
                const int tt = rem / 5, s = rem % 5;
                const int krow = s * 32 + k;
                if (krow < 144) v = Wm[m * 4608 + krow * 32 + tt * 16 + row];
            } else if (b < 180) {               // root: tt*9 + s
                const int idx = b - 144, tt = idx / 9, s = idx % 9;
                if (s == 0) { if (k < 16) v = Wr[k * 64 + tt * 16 + row]; }
                else { const int krow = 16 + (s - 1) * 32 + k;
                       v = Wr[krow * 64 + tt * 16 + row]; }
            } else {                            // head
                const int s = b - 180, krow = s * 32 + k;
                if (row < 10) v = Wh[krow * 10 + row];
            }
            vals[i] = f2bf(v);
        }
        #pragma unroll
        for (int i = 0; i < 8; ++i) wsFrag[b * 512 + t * 8 + i] = vals[i];
    } else if (b == N_FRAG_BLOCKS) {            // leaf ST (1024), folded by K2L
        for (int i = 0; i < 16; ++i) {
            const int id = t + 64 * i;
            const float S = gl[id] * rsqrtf(vl[id] + EPS);
            wsST[ST_SL + id] = S * K2L;
            wsST[ST_TL + id] = ((bl[id] - ml[id]) * S + betal[id]) * K2L;
        }
    } else if (b == N_FRAG_BLOCKS + 1) {        // mid ST (256)
        for (int i = 0; i < 4; ++i) {
            const int id = t + 64 * i;
            const float S = gm[id] * rsqrtf(vm[id] + EPS);
            wsST[ST_SM + id] = S * K2L;
            wsST[ST_TM + id] = ((bm[id] - mm[id]) * S + betam[id]) * K2L;
        }
    } else {                                     // root ST (64)
        const int id = t;
        const float S = gr[id] * rsqrtf(vr[id] + EPS);
        wsST[ST_SR + id] = S * K2L;
        wsST[ST_TR + id] = ((br[id] - mr[id]) * S + betar[id]) * K2L;
    }
}

// ---------------- main fused MFMA kernel: 1 mid per wave -------------------
// Block = 512 thr = 8 waves = one 16-sample tile; wave w owns mid w entirely
// (8 leaves -> mid -> hm in LDS). Root + head run at the combine tail (waves
// 0..3 read all 8 hm slabs as B-frags). 8192 waves = 32/CU = 8 waves/SIMD.
// LDS = exactly 40960 B -> 4 blocks/CU (full 2048 threads). 2 barriers.
__global__ __launch_bounds__(512, 8) void ontology_mfma(
    const float* __restrict__ x,
    const unsigned short* __restrict__ wsFrag,
    const float* __restrict__ wsST,
    const float* __restrict__ bh,
    float* __restrict__ out)
{
    // one slab; per-wave region = 2560 u16 (5120 B). mid_in[w][c][col] at
    // w*2560 + c*160 + col. hm[w] aliases own region (cols 0..39 of rows,
    // written after all own mid reads). hr aliases wave7 region +1280 u16.
    __shared__ __align__(16) unsigned short lds[8 * 2560];   // 40960 B exact

    const int tid  = threadIdx.x;
    const int w    = tid >> 6;
    const int lane = tid & 63;
    const int c    = lane & 15;       // sample within tile
    const int g    = lane >> 4;       // k/feat group
    const int rowbase = blockIdx.x * 16;
    const float* xrow = x + (size_t)(rowbase + c) * 1168;

    unsigned short* my = lds + w * 2560;            // own region (u16 units)
    unsigned short* hr = lds + 7 * 2560 + 1280;     // [16][72] u16 = 2304 B

    const float* Sl = wsST + ST_SL; const float* Tl = wsST + ST_TL;
    const float* Sm = wsST + ST_SM; const float* Tm = wsST + ST_TM;
    const float* Sr = wsST + ST_SR; const float* Tr = wsST + ST_TR;

    // zero own K-pad cols 144..159 (read by mid s=4)
    { uint2 z; z.x = 0u; z.y = 0u;
      *(uint2*)(my + c * 160 + 144 + 4 * g) = z; }

    // ---- x loads for mid w ----
    float4 xm4 = *(const float4*)(xrow + 1024 + w * 16 + 4 * g);
    float4 xp[4][2];
    #pragma unroll
    for (int p = 0; p < 4; ++p) {
        const float* a = xrow + (w * 4 + p) * 32 + g * 8;
        xp[p][0] = *(const float4*)a;
        xp[p][1] = *(const float4*)(a + 4);
    }

    // xm -> mid_in cols 0..15
    { uint2 pm; pm.x = pack2bf(xm4.x, xm4.y); pm.y = pack2bf(xm4.z, xm4.w);
      *(uint2*)(my + c * 160 + 4 * g) = pm; }

    // ---- 8 leaves (pair p shares packed B-frag) ----
    #pragma unroll
    for (int p = 0; p < 4; ++p) {
        bf16x8 bfrag = pack8(xp[p][0], xp[p][1]);
        #pragma unroll
        for (int e = 0; e < 2; ++e) {
            const int l = 2 * p + e, leaf = w * 8 + l;
            bf16x8 afrag = *(const bf16x8*)(wsFrag + (WSB_LEAF + leaf) * 512 + lane * 8);
            f32x4 zz = {0.f,0.f,0.f,0.f};
            f32x4 acc = __builtin_amdgcn_mfma_f32_16x16x32_bf16(afrag, bfrag, zz, 0, 0, 0);
            const int po = leaf * 16 + 4 * g;
            float4 S = *(const float4*)(Sl + po);
            float4 T = *(const float4*)(Tl + po);
            uint2 pk;
            pk.x = pack2bf(bn_act(acc[0], S.x, T.x), bn_act(acc[1], S.y, T.y));
            pk.y = pack2bf(bn_act(acc[2], S.z, T.z), bn_act(acc[3], S.w, T.w));
            *(uint2*)(my + c * 160 + 16 + l * 16 + 4 * g) = pk;
        }
    }

    // ---- mid w: both col-tiles share each bfrag (5 ds_reads total) ----
    {
        f32x4 acc0 = {0.f,0.f,0.f,0.f};
        f32x4 acc1 = {0.f,0.f,0.f,0.f};
        const unsigned short* fb = wsFrag + (WSB_MID + w * 10) * 512 + lane * 8;
        #pragma unroll
        for (int s = 0; s < 5; ++s) {
            bf16x8 bfrag = *(const bf16x8*)(my + c * 160 + s * 32 + g * 8);
            bf16x8 a0 = *(const bf16x8*)(fb + s * 512);
            bf16x8 a1 = *(const bf16x8*)(fb + (5 + s) * 512);
            acc0 = __builtin_amdgcn_mfma_f32_16x16x32_bf16(a0, bfrag, acc0, 0, 0, 0);
            acc1 = __builtin_amdgcn_mfma_f32_16x16x32_bf16(a1, bfrag, acc1, 0, 0, 0);
        }
        // hm[w] aliases own region cols 0..39 (all own mid reads done)
        #pragma unroll
        for (int tt = 0; tt < 2; ++tt) {
            f32x4 acc = tt ? acc1 : acc0;
            const int po = w * 32 + tt * 16 + 4 * g;
            float4 S = *(const float4*)(Sm + po);
            float4 T = *(const float4*)(Tm + po);
            uint2 pk;
            pk.x = pack2bf(bn_act(acc[0], S.x, T.x), bn_act(acc[1], S.y, T.y));
            pk.y = pack2bf(bn_act(acc[2], S.z, T.z), bn_act(acc[3], S.w, T.w));
            *(uint2*)(my + c * 40 + tt * 16 + 4 * g) = pk;
        }
    }

    // root x-slice loads (readers only), issued before the barrier wait
    float4 xrA, xrB;
    if (w < 4) {
        const float* rp = xrow + 1152 + (g & 1) * 8;
        xrA = *(const float4*)rp;
        xrB = *(const float4*)(rp + 4);
    }

    __syncthreads();   // barrier 1: all hm slabs visible

    // ---- root col-tile w (waves 0..3): s=0 from x, s=1..8 from hm[v] ----
    if (w < 4) {
        const unsigned short* fb = wsFrag + (WSB_ROOT + w * 9) * 512 + lane * 8;
        f32x4 acc = {0.f,0.f,0.f,0.f};
        {
            bf16x8 bfrag = pack8(xrA, xrB);
            bf16x8 a0 = *(const bf16x8*)fb;
            acc = __builtin_amdgcn_mfma_f32_16x16x32_bf16(a0, bfrag, acc, 0, 0, 0);
        }
        #pragma unroll
        for (int s = 1; s <= 8; ++s) {
            bf16x8 bfrag = *(const bf16x8*)(lds + (s - 1) * 2560 + c * 40 + g * 8);
            bf16x8 a0 = *(const bf16x8*)(fb + s * 512);
            acc = __builtin_amdgcn_mfma_f32_16x16x32_bf16(a0, bfrag, acc, 0, 0, 0);
        }
        const int po = w * 16 + 4 * g;
        float4 S = *(const float4*)(Sr + po);
        float4 T = *(const float4*)(Tr + po);
        uint2 pk;
        pk.x = pack2bf(bn_act(acc[0], S.x, T.x), bn_act(acc[1], S.y, T.y));
        pk.y = pack2bf(bn_act(acc[2], S.z, T.z), bn_act(acc[3], S.w, T.w));
        *(uint2*)(hr + c * 72 + w * 16 + 4 * g) = pk;
    }

    __syncthreads();   // barrier 2: hr complete

    // ---- head (wave 0): tasks in rows, samples in cols ----
    if (w == 0) {
        f32x4 acc = {0.f,0.f,0.f,0.f};
        #pragma unroll
        for (int s = 0; s < 2; ++s) {
            bf16x8 bfrag = *(const bf16x8*)(hr + c * 72 + s * 32 + g * 8);
            bf16x8 a0 = *(const bf16x8*)(wsFrag + (WSB_HEAD + s) * 512 + lane * 8);
            acc = __builtin_amdgcn_mfma_f32_16x16x32_bf16(a0, bfrag, acc, 0, 0, 0);
        }
        float* op = out + (size_t)(rowbase + c) * 10 + 4 * g;
        if (g < 2) {
            float2 o1 = {acc[0] + bh[4 * g],     acc[1] + bh[4 * g + 1]};
            float2 o2 = {acc[2] + bh[4 * g + 2], acc[3] + bh[4 * g + 3]};
            *(float2*)op = o1;
            *(float2*)(op + 2) = o2;
        } else if (g == 2) {
            float2 o1 = {acc[0] + bh[8], acc[1] + bh[9]};
            *(float2*)op = o1;
        }
    }
}

extern "C" void kernel_launch(void* const* d_in, const int* in_sizes, int n_in,
                              void* d_out, int out_size, void* d_ws, size_t ws_size,
                              hipStream_t stream) {
    const float* x     = (const float*)d_in[0];
    const float* Wl    = (const float*)d_in[1];
    const float* bl    = (const float*)d_in[2];
    const float* gl    = (const float*)d_in[3];
    const float* betal = (const float*)d_in[4];
    const float* ml    = (const float*)d_in[5];
    const float* vl    = (const float*)d_in[6];
    const float* Wm    = (const float*)d_in[7];
    const float* bm    = (const float*)d_in[8];
    const float* gm    = (const float*)d_in[9];
    const float* betam = (const float*)d_in[10];
    const float* mm    = (const float*)d_in[11];
    const float* vm    = (const float*)d_in[12];
    const float* Wr    = (const float*)d_in[13];
    const float* br    = (const float*)d_in[14];
    const float* gr    = (const float*)d_in[15];
    const float* betar = (const float*)d_in[16];
    const float* mr    = (const float*)d_in[17];
    const float* vr    = (const float*)d_in[18];
    const float* Wh    = (const float*)d_in[19];
    const float* bh    = (const float*)d_in[20];
    float* out = (float*)d_out;

    unsigned short* wsFrag = (unsigned short*)d_ws;
    float* wsST = (float*)((char*)d_ws + WS_ST_BYTE_OFF);

    ontology_prep<<<N_FRAG_BLOCKS + 3, 64, 0, stream>>>(
        Wl, Wm, Wr, Wh, bl, gl, betal, ml, vl, bm, gm, betam, mm, vm,
        br, gr, betar, mr, vr, wsFrag, wsST);

    const int n = in_sizes[0] / 1168;   // 16384
    ontology_mfma<<<n / 16, 512, 0, stream>>>(x, wsFrag, wsST, bh, out);
}